// Round 7
// baseline (515.130 us; speedup 1.0000x reference)
//
#include <hip/hip_runtime.h>
#include <cstdint>
#include <cstddef>

typedef __attribute__((ext_vector_type(8))) short short8;
typedef __attribute__((ext_vector_type(4))) float f32x4;
typedef __attribute__((ext_vector_type(4))) unsigned short ushort4v;

#define E_DIM 1024
#define D_DIM 64
#define H_DIM 16
#define F_DIM 4096
#define B_DIM 2
#define S_DIM 2048
#define M_DIM 4096
#define LN_EPS 1e-5f
#define LOG2E 1.4426950408889634f

__device__ __forceinline__ float bf2f(unsigned short u) {
  union { unsigned int i; float f; } v;
  v.i = ((unsigned int)u) << 16;
  return v.f;
}
__device__ __forceinline__ unsigned short f2bf(float f) {
  union { float f; unsigned int i; } v;
  v.f = f;
  unsigned int r = v.i + 0x7FFFu + ((v.i >> 16) & 1u);
  return (unsigned short)(r >> 16);
}
// packed f32x2 -> bf16x2 (low word = a, high word = b), RNE
__device__ __forceinline__ unsigned int cvt_pk_bf16(float a, float b) {
  unsigned int r;
  asm("v_cvt_pk_bf16_f32 %0, %1, %2" : "=v"(r) : "v"(a), "v"(b));
  return r;
}
__device__ __forceinline__ float exp2_fast(float x) {
  float r;
  asm("v_exp_f32 %0, %1" : "=v"(r) : "v"(x));
  return r;
}

__device__ __forceinline__ void gload_lds16(const unsigned short* src,
                                            unsigned short* dst) {
  __builtin_amdgcn_global_load_lds(
      (const __attribute__((address_space(1))) void*)src,
      (__attribute__((address_space(3))) void*)dst, 16, 0, 0);
}

// ---------------------------------------------------------------------------
// All weight transposes in ONE launch. fp32 [R][C] -> bf16 [C][R].
// block id ranges: [0,3072) Wq/Wk/Wv (QKV [H][E][D] addressing),
// [3072,4096) Wo, [4096,8192) W1, [8192,12288) W2.
// ---------------------------------------------------------------------------
__global__ __launch_bounds__(256) void transpose_all(
    const float* __restrict__ Wq, const float* __restrict__ Wk,
    const float* __restrict__ Wv, const float* __restrict__ Wo,
    const float* __restrict__ W1, const float* __restrict__ W2,
    unsigned short* __restrict__ WqkvT, unsigned short* __restrict__ WoT,
    unsigned short* __restrict__ W1T, unsigned short* __restrict__ W2T) {
  int id = blockIdx.x;
  const float* in;
  unsigned short* out;
  int R, C;
  bool qkv = false;
  float scale = 1.f;
  if (id < 3072) {
    int seg = id >> 10;
    in = seg == 0 ? Wq : seg == 1 ? Wk : Wv;
    out = WqkvT + (size_t)seg * 1048576;
    R = 1024; C = 1024; qkv = true;
    if (seg == 0) scale = LOG2E;
    id &= 1023;
  } else if (id < 4096) {
    in = Wo; out = WoT; R = 1024; C = 1024; id -= 3072;
  } else if (id < 8192) {
    in = W1; out = W1T; R = 1024; C = 4096; id -= 4096;
  } else {
    in = W2; out = W2T; R = 4096; C = 1024; id -= 8192;
  }
  const int tpc = C >> 5;
  const int c0 = (id % tpc) * 32, r0 = (id / tpc) * 32;
  __shared__ float t[32][33];
  const int tid = threadIdx.x;
  {
    const int rr = tid >> 3, c4 = (tid & 7) * 4;
    size_t addr;
    if (qkv)
      addr = (size_t)(c0 >> 6) * 65536 + (size_t)(r0 + rr) * 64 +
             ((c0 & 63) + c4);
    else
      addr = (size_t)(r0 + rr) * C + (c0 + c4);
    float4 v = *(const float4*)(in + addr);
    t[rr][c4 + 0] = v.x;
    t[rr][c4 + 1] = v.y;
    t[rr][c4 + 2] = v.z;
    t[rr][c4 + 3] = v.w;
  }
  __syncthreads();
  {
    const int cc = tid >> 3, k4 = (tid & 7) * 4;
    ushort4v hi;
    hi.x = f2bf(t[k4 + 0][cc] * scale);
    hi.y = f2bf(t[k4 + 1][cc] * scale);
    hi.z = f2bf(t[k4 + 2][cc] * scale);
    hi.w = f2bf(t[k4 + 3][cc] * scale);
    *(ushort4v*)(out + (size_t)(c0 + cc) * R + (r0 + k4)) = hi;
  }
}

// ---------------------------------------------------------------------------
// LayerNorm fp32 in -> bf16 out
// ---------------------------------------------------------------------------
__global__ __launch_bounds__(256) void ln_kernel(const float* __restrict__ x,
                                                 const float* __restrict__ g,
                                                 const float* __restrict__ b,
                                                 unsigned short* __restrict__ o) {
  const int row = blockIdx.x;
  const float* xp = x + (size_t)row * E_DIM;
  const int t4 = threadIdx.x * 4;
  float4 xv = *(const float4*)(xp + t4);
  float s = xv.x + xv.y + xv.z + xv.w;
  float ss = xv.x * xv.x + xv.y * xv.y + xv.z * xv.z + xv.w * xv.w;
#pragma unroll
  for (int off = 32; off > 0; off >>= 1) {
    s += __shfl_down(s, off);
    ss += __shfl_down(ss, off);
  }
  __shared__ float red[8];
  const int wid = threadIdx.x >> 6;
  if ((threadIdx.x & 63) == 0) {
    red[wid] = s;
    red[4 + wid] = ss;
  }
  __syncthreads();
  if (threadIdx.x == 0) {
    float S = red[0] + red[1] + red[2] + red[3];
    float SS = red[4] + red[5] + red[6] + red[7];
    float mean = S * (1.0f / E_DIM);
    float var = SS * (1.0f / E_DIM) - mean * mean;
    red[0] = mean;
    red[1] = rsqrtf(var + LN_EPS);
  }
  __syncthreads();
  const float mean = red[0], rstd = red[1];
  float4 gv = *(const float4*)(g + t4);
  float4 bv = *(const float4*)(b + t4);
  ushort4v hi;
  hi.x = f2bf((xv.x - mean) * rstd * gv.x + bv.x);
  hi.y = f2bf((xv.y - mean) * rstd * gv.y + bv.y);
  hi.z = f2bf((xv.z - mean) * rstd * gv.z + bv.z);
  hi.w = f2bf((xv.w - mean) * rstd * gv.w + bv.w);
  *(ushort4v*)(o + (size_t)row * E_DIM + t4) = hi;
}

// ---------------------------------------------------------------------------
// MFMA GEMM: C[M,N] = A[M,K] * B^T (B stored [N][K], bf16).
// m97 structure: 128x128 tile, BK=64, 4 waves, SINGLE 32KB LDS buffer,
// 2 barriers/K-step (implicit multi-block overlap is the pipeline — dbuf at
// 64KB LDS capped occupancy at 2 blocks/CU and regressed, r5).
// Fragment-ordered LDS: chunk(rb,kc)=1024B wave-linear frag; 0 bank conflicts
// (verified r4/r5). Bijective XCD-chunked swizzle (FETCH 135->49MB, r5).
// MODE 0: fused QKV: n<1024 -> Q[pair][s][d] (log2e-scaled); <2048 -> K;
//         else Vt[pair][d][s]
// MODE 3: bf16 out = relu(acc + bias[n])               (W1)
// MODE 4: split-K over gridDim.z: atomicAdd fp32 out += acc  (Wo, W2)
// ---------------------------------------------------------------------------
template <int MODE>
__global__ __launch_bounds__(256) void mfma_gemm(
    const unsigned short* __restrict__ A, const unsigned short* __restrict__ B,
    const float* __restrict__ bias, const float* __restrict__ bias2,
    const float* __restrict__ bias3, void* __restrict__ out0,
    void* __restrict__ out1, void* __restrict__ out2, int M, int N, int K) {
  __shared__ unsigned short As[8192];
  __shared__ unsigned short Bs[8192];
  const int tid = threadIdx.x;
  // XCD-chunked swizzle: contiguous swz-range per XCD -> A-panel L2 reuse.
  // nwg % 8 == 0 for all launches (256/768/1024).
  const int nwg = gridDim.x * gridDim.y;
  const int flat = blockIdx.y * gridDim.x + blockIdx.x;
  const int swz = (flat & 7) * (nwg >> 3) + (flat >> 3);
  const int m0 = (swz / gridDim.x) * 128, n0 = (swz % gridDim.x) * 128;
  const int lane = tid & 63, wid = tid >> 6;
  const int wr = wid >> 1, wc = wid & 1;
  const int lr = lane & 15, lg = lane >> 4;

  f32x4 acc[4][4];
#pragma unroll
  for (int i = 0; i < 4; ++i)
#pragma unroll
    for (int j = 0; j < 4; ++j) acc[i][j] = {0.f, 0.f, 0.f, 0.f};

  int kbeg = 0, kend = K;
  if constexpr (MODE == 4) {
    int kslice = K / gridDim.z;
    kbeg = blockIdx.z * kslice;
    kend = kbeg + kslice;
  }

  for (int k0 = kbeg; k0 < kend; k0 += 64) {
#pragma unroll
    for (int c = 0; c < 4; ++c) {
      int chunk = wid * 4 + c;  // 0..15; rb = chunk>>1, kc = chunk&1
      int rb = chunk >> 1, kc = chunk & 1;
      size_t goff = (size_t)(rb * 16 + lr) * K + k0 + kc * 32 + lg * 8;
      gload_lds16(A + (size_t)m0 * K + goff, As + chunk * 512);
      gload_lds16(B + (size_t)n0 * K + goff, Bs + chunk * 512);
    }
    __syncthreads();
#pragma unroll
    for (int kc = 0; kc < 2; ++kc) {
      short8 af[4], bf[4];
#pragma unroll
      for (int mi = 0; mi < 4; ++mi)
        af[mi] = *(const short8*)(As + ((wr * 4 + mi) * 2 + kc) * 512 + lane * 8);
#pragma unroll
      for (int ni = 0; ni < 4; ++ni)
        bf[ni] = *(const short8*)(Bs + ((wc * 4 + ni) * 2 + kc) * 512 + lane * 8);
#pragma unroll
      for (int mi = 0; mi < 4; ++mi)
#pragma unroll
        for (int ni = 0; ni < 4; ++ni)
          acc[mi][ni] = __builtin_amdgcn_mfma_f32_16x16x32_bf16(
              af[mi], bf[ni], acc[mi][ni], 0, 0, 0);
    }
    __syncthreads();
  }
  // epilogue — C/D layout: col = lane&15, row = (lane>>4)*4 + reg
#pragma unroll
  for (int mi = 0; mi < 4; ++mi) {
#pragma unroll
    for (int ni = 0; ni < 4; ++ni) {
      int n = n0 + wc * 64 + ni * 16 + lr;
#pragma unroll
      for (int rr = 0; rr < 4; ++rr) {
        int m = m0 + wr * 64 + mi * 16 + lg * 4 + rr;
        float v = acc[mi][ni][rr];
        if constexpr (MODE == 0) {
          int seg = n >> 10, nn = n & 1023;
          const float* bp = seg == 0 ? bias : seg == 1 ? bias2 : bias3;
          v += (seg == 0) ? bp[nn] * LOG2E : bp[nn];
          int hh = nn >> 6, d = nn & 63, bb = m >> 11, srow = m & 2047;
          size_t pb = (size_t)(hh * 2 + bb) * 131072;
          if (seg == 0)
            ((unsigned short*)out0)[pb + (size_t)srow * 64 + d] = f2bf(v);
          else if (seg == 1)
            ((unsigned short*)out1)[pb + (size_t)srow * 64 + d] = f2bf(v);
          else
            ((unsigned short*)out2)[pb + (size_t)d * 2048 + srow] = f2bf(v);
        } else if constexpr (MODE == 3) {
          ((unsigned short*)out0)[(size_t)m * N + n] = f2bf(fmaxf(v + bias[n], 0.f));
        } else {
          unsafeAtomicAdd((float*)out0 + (size_t)m * N + n, v);
        }
      }
    }
  }
}

// ---------------------------------------------------------------------------
// Attention (quirk-faithful): scores = K·Q^T unscaled, softmax over query t.
// Logits arrive in exp2 domain (Wq,bq pre-scaled by log2e).
// S^T = Q·K^T: lane owns ONE s-column; softmax = 2 cross-lane reduces;
// P^T B-frags for PV via lane shuffle (no LDS P). Fragment-ordered LDS tiles.
// Q,K: [pair][2048][64] bf16; Vt: [pair][64][2048]. O: [4096][1024] bf16.
// ---------------------------------------------------------------------------
__global__ __launch_bounds__(256, 4) void attn_mfma(
    const unsigned short* __restrict__ Q, const unsigned short* __restrict__ K,
    const unsigned short* __restrict__ Vt, unsigned short* __restrict__ O) {
  __shared__ unsigned short Qs[2][4096];
  __shared__ unsigned short Vs[2][4096];
  const int bid = blockIdx.x;
  const int wg = (bid & 7) * 128 + (bid >> 3);  // XCD-chunked swizzle (1024%8==0)
  const int pair = wg >> 5, stile = wg & 31;
  const int tid = threadIdx.x, lane = tid & 63, wid = tid >> 6;
  const int lr = lane & 15, lg = lane >> 4;
  const size_t pbase = (size_t)pair * 131072;

  const int s_own = stile * 64 + wid * 16 + lr;
  short8 kb[2];  // B-frag: col s = lr-owned, k = d
#pragma unroll
  for (int c = 0; c < 2; ++c)
    kb[c] = *(const short8*)(K + pbase + (size_t)s_own * 64 + c * 32 + lg * 8);

  f32x4 oa[4];
#pragma unroll
  for (int i = 0; i < 4; ++i) oa[i] = {0.f, 0.f, 0.f, 0.f};
  float mrun = -3e38f, lrun = 0.f;

  // frag-ordered staging: chunk = wid*2+c holds (rowblk=wid, kc=c), lane-linear
  auto stage = [&](int buf, int t0) {
#pragma unroll
    for (int c = 0; c < 2; ++c) {
      int chunk = wid * 2 + c;
      gload_lds16(Q + pbase + (size_t)(t0 + wid * 16 + lr) * 64 + c * 32 + lg * 8,
                  &Qs[buf][chunk * 512]);
      gload_lds16(Vt + pbase + (size_t)(wid * 16 + lr) * 2048 + t0 + c * 32 + lg * 8,
                  &Vs[buf][chunk * 512]);
    }
  };

  stage(0, 0);
  __syncthreads();

  for (int it = 0; it < 32; ++it) {
    const int cur = it & 1;
    if (it < 31) stage(cur ^ 1, (it + 1) * 64);

    // S^T tile: sacc[j][r] = S[t = j*16 + lg*4 + r][s = lr]  (log2 domain)
    f32x4 sacc[4];
#pragma unroll
    for (int j = 0; j < 4; ++j) {
      sacc[j] = {0.f, 0.f, 0.f, 0.f};
      __builtin_amdgcn_s_setprio(1);
#pragma unroll
      for (int c = 0; c < 2; ++c) {
        short8 aq = *(const short8*)(&Qs[cur][(j * 2 + c) * 512 + lane * 8]);
        sacc[j] = __builtin_amdgcn_mfma_f32_16x16x32_bf16(aq, kb[c], sacc[j], 0, 0, 0);
      }
      __builtin_amdgcn_s_setprio(0);
    }
    // online softmax (exp2 domain) with defer-max
    float tm = fmaxf(
        fmaxf(fmaxf(fmaxf(sacc[0][0], sacc[0][1]), fmaxf(sacc[0][2], sacc[0][3])),
              fmaxf(fmaxf(sacc[1][0], sacc[1][1]), fmaxf(sacc[1][2], sacc[1][3]))),
        fmaxf(fmaxf(fmaxf(sacc[2][0], sacc[2][1]), fmaxf(sacc[2][2], sacc[2][3])),
              fmaxf(fmaxf(sacc[3][0], sacc[3][1]), fmaxf(sacc[3][2], sacc[3][3]))));
    tm = fmaxf(tm, __shfl_xor(tm, 16));
    tm = fmaxf(tm, __shfl_xor(tm, 32));
    if (!__all(tm - mrun <= 11.0f)) {  // rescale path (rare after warm-up)
      float mnew = fmaxf(mrun, tm);
      float sc = exp2_fast(mrun - mnew);
      mrun = mnew;
      lrun *= sc;
#pragma unroll
      for (int di = 0; di < 4; ++di) {
        f32x4 t = oa[di];
        t[0] *= sc; t[1] *= sc; t[2] *= sc; t[3] *= sc;
        oa[di] = t;
      }
    }
    float p[4][4];
#pragma unroll
    for (int j = 0; j < 4; ++j)
#pragma unroll
      for (int r = 0; r < 4; ++r) p[j][r] = exp2_fast(sacc[j][r] - mrun);
    float lsum = ((p[0][0] + p[0][1]) + (p[0][2] + p[0][3])) +
                 ((p[1][0] + p[1][1]) + (p[1][2] + p[1][3])) +
                 ((p[2][0] + p[2][1]) + (p[2][2] + p[2][3])) +
                 ((p[3][0] + p[3][1]) + (p[3][2] + p[3][3]));
    lsum += __shfl_xor(lsum, 16);
    lsum += __shfl_xor(lsum, 32);
    lrun += lsum;
    // pack P rows (bf16 pairs) for shuffle-transpose
    unsigned int pw[4][2];
#pragma unroll
    for (int j = 0; j < 4; ++j) {
      pw[j][0] = cvt_pk_bf16(p[j][0], p[j][1]);
      pw[j][1] = cvt_pk_bf16(p[j][2], p[j][3]);
    }
    // PV: O^T[d][s] += Vt[d][t] * P^T[t][s]
#pragma unroll
    for (int kc = 0; kc < 2; ++kc) {
      unsigned int bw[4];
#pragma unroll
      for (int mm = 0; mm < 4; ++mm) {
        int src = ((lg & 1) * 2 + (mm >> 1)) * 16 + lr;
        int lo = __shfl((int)pw[2 * kc][mm & 1], src, 64);
        int hi = __shfl((int)pw[2 * kc + 1][mm & 1], src, 64);
        bw[mm] = (lg & 2) ? (unsigned)hi : (unsigned)lo;
      }
      union { unsigned int u[4]; short8 s8; } pb;
      pb.u[0] = bw[0]; pb.u[1] = bw[1]; pb.u[2] = bw[2]; pb.u[3] = bw[3];
      __builtin_amdgcn_s_setprio(1);
#pragma unroll
      for (int di = 0; di < 4; ++di) {
        short8 vf = *(const short8*)(&Vs[cur][(di * 2 + kc) * 512 + lane * 8]);
        oa[di] = __builtin_amdgcn_mfma_f32_16x16x32_bf16(vf, pb.s8, oa[di], 0, 0, 0);
      }
      __builtin_amdgcn_s_setprio(0);
    }
    __syncthreads();
  }

  const float inv = 1.f / lrun;
  const int b = pair & 1, h = pair >> 1;
  unsigned short* op = O + ((size_t)(b * 2048 + s_own)) * 1024 + h * 64;
#pragma unroll
  for (int di = 0; di < 4; ++di) {
    unsigned int w0 = cvt_pk_bf16(oa[di][0] * inv, oa[di][1] * inv);
    unsigned int w1 = cvt_pk_bf16(oa[di][2] * inv, oa[di][3] * inv);
    *(unsigned int*)(op + di * 16 + lg * 4) = w0;
    *(unsigned int*)(op + di * 16 + lg * 4 + 2) = w1;
  }
}

// ---------------------------------------------------------------------------
// init out = resid + bias (row length 1024 fp32), before split-K atomics
// ---------------------------------------------------------------------------
__global__ __launch_bounds__(256) void init_acc(const float* __restrict__ resid,
                                                const float* __restrict__ bias,
                                                float* __restrict__ out) {
  int i = blockIdx.x * 256 + threadIdx.x;  // float4 index; row = 256 float4
  float4 v = ((const float4*)resid)[i];
  float4 bb = ((const float4*)bias)[i & 255];
  v.x += bb.x; v.y += bb.y; v.z += bb.z; v.w += bb.w;
  ((float4*)out)[i] = v;
}

// ---------------------------------------------------------------------------
extern "C" void kernel_launch(void* const* d_in, const int* in_sizes, int n_in,
                              void* d_out, int out_size, void* d_ws,
                              size_t ws_size, hipStream_t stream) {
  const float* x = (const float*)d_in[0];
  const float* Wq = (const float*)d_in[1];
  const float* bq = (const float*)d_in[2];
  const float* Wk = (const float*)d_in[3];
  const float* bk = (const float*)d_in[4];
  const float* Wv = (const float*)d_in[5];
  const float* bv = (const float*)d_in[6];
  const float* Wo = (const float*)d_in[7];
  const float* bo = (const float*)d_in[8];
  const float* ln1_g = (const float*)d_in[9];
  const float* ln1_b = (const float*)d_in[10];
  const float* ln2_g = (const float*)d_in[11];
  const float* ln2_b = (const float*)d_in[12];
  const float* W1 = (const float*)d_in[13];
  const float* b1 = (const float*)d_in[14];
  const float* W2 = (const float*)d_in[15];
  const float* b2 = (const float*)d_in[16];

  char* w = (char*)d_ws;
  const size_t MB = 1024 * 1024;
  unsigned short* WqkvT = (unsigned short*)(w + 0 * MB);  // [3072][1024]
  unsigned short* WoT = (unsigned short*)(w + 6 * MB);    // [1024][1024]
  unsigned short* W1T = (unsigned short*)(w + 8 * MB);    // [4096][1024]
  unsigned short* W2T = (unsigned short*)(w + 16 * MB);   // [1024][4096]
  unsigned short* h = (unsigned short*)(w + 24 * MB);     // [4096][1024]
  unsigned short* Qb = (unsigned short*)(w + 32 * MB);    // [32][2048][64]
  unsigned short* Kb = (unsigned short*)(w + 40 * MB);
  unsigned short* Vt = (unsigned short*)(w + 48 * MB);    // [32][64][2048]
  unsigned short* Obuf = (unsigned short*)(w + 56 * MB);  // [4096][1024]
  unsigned short* m1 = (unsigned short*)(w + 32 * MB);    // [4096][4096], aliases Qb..Obuf
  float* x2 = (float*)(w + 64 * MB);                      // [4096][1024] fp32

  const dim3 blk(256);

  transpose_all<<<12288, blk, 0, stream>>>(Wq, Wk, Wv, Wo, W1, W2, WqkvT, WoT,
                                           W1T, W2T);

  ln_kernel<<<M_DIM, blk, 0, stream>>>(x, ln1_g, ln1_b, h);

  mfma_gemm<0><<<dim3(24, 32), blk, 0, stream>>>(h, WqkvT, bq, bk, bv, Qb, Kb,
                                                 Vt, M_DIM, 3072, 1024);

  attn_mfma<<<1024, blk, 0, stream>>>(Qb, Kb, Vt, Obuf);

  init_acc<<<4096, blk, 0, stream>>>(x, bo, x2);
  mfma_gemm<4><<<dim3(8, 32, 2), blk, 0, stream>>>(Obuf, WoT, nullptr, nullptr,
                                                   nullptr, x2, nullptr,
                                                   nullptr, M_DIM, 1024, 1024);

  ln_kernel<<<M_DIM, blk, 0, stream>>>(x2, ln2_g, ln2_b, h);

  mfma_gemm<3><<<dim3(32, 32), blk, 0, stream>>>(h, W1T, b1, nullptr, nullptr,
                                                 m1, nullptr, nullptr, M_DIM,
                                                 4096, 1024);

  init_acc<<<4096, blk, 0, stream>>>(x2, b2, (float*)d_out);
  mfma_gemm<4><<<dim3(8, 32, 4), blk, 0, stream>>>(
      m1, W2T, nullptr, nullptr, nullptr, (float*)d_out, nullptr, nullptr,
      M_DIM, 1024, 4096);
}

// Round 8
// 474.560 us; speedup vs baseline: 1.0855x; 1.0855x over previous
//
#include <hip/hip_runtime.h>
#include <cstdint>
#include <cstddef>

typedef __attribute__((ext_vector_type(8))) short short8;
typedef __attribute__((ext_vector_type(4))) float f32x4;
typedef __attribute__((ext_vector_type(4))) unsigned short ushort4v;

#define E_DIM 1024
#define D_DIM 64
#define H_DIM 16
#define F_DIM 4096
#define B_DIM 2
#define S_DIM 2048
#define M_DIM 4096
#define LN_EPS 1e-5f
#define LOG2E 1.4426950408889634f

__device__ __forceinline__ float bf2f(unsigned short u) {
  union { unsigned int i; float f; } v;
  v.i = ((unsigned int)u) << 16;
  return v.f;
}
__device__ __forceinline__ unsigned short f2bf(float f) {
  union { float f; unsigned int i; } v;
  v.f = f;
  unsigned int r = v.i + 0x7FFFu + ((v.i >> 16) & 1u);
  return (unsigned short)(r >> 16);
}
// packed f32x2 -> bf16x2 (low word = a, high word = b), RNE
__device__ __forceinline__ unsigned int cvt_pk_bf16(float a, float b) {
  unsigned int r;
  asm("v_cvt_pk_bf16_f32 %0, %1, %2" : "=v"(r) : "v"(a), "v"(b));
  return r;
}
__device__ __forceinline__ float exp2_fast(float x) {
  float r;
  asm("v_exp_f32 %0, %1" : "=v"(r) : "v"(x));
  return r;
}

__device__ __forceinline__ void gload_lds16(const unsigned short* src,
                                            unsigned short* dst) {
  __builtin_amdgcn_global_load_lds(
      (const __attribute__((address_space(1))) void*)src,
      (__attribute__((address_space(3))) void*)dst, 16, 0, 0);
}

// ---------------------------------------------------------------------------
// All weight transposes in ONE launch. fp32 [R][C] -> bf16 [C][R].
// block id ranges: [0,3072) Wq/Wk/Wv (QKV [H][E][D] addressing),
// [3072,4096) Wo, [4096,8192) W1, [8192,12288) W2.
// ---------------------------------------------------------------------------
__global__ __launch_bounds__(256) void transpose_all(
    const float* __restrict__ Wq, const float* __restrict__ Wk,
    const float* __restrict__ Wv, const float* __restrict__ Wo,
    const float* __restrict__ W1, const float* __restrict__ W2,
    unsigned short* __restrict__ WqkvT, unsigned short* __restrict__ WoT,
    unsigned short* __restrict__ W1T, unsigned short* __restrict__ W2T) {
  int id = blockIdx.x;
  const float* in;
  unsigned short* out;
  int R, C;
  bool qkv = false;
  float scale = 1.f;
  if (id < 3072) {
    int seg = id >> 10;
    in = seg == 0 ? Wq : seg == 1 ? Wk : Wv;
    out = WqkvT + (size_t)seg * 1048576;
    R = 1024; C = 1024; qkv = true;
    if (seg == 0) scale = LOG2E;
    id &= 1023;
  } else if (id < 4096) {
    in = Wo; out = WoT; R = 1024; C = 1024; id -= 3072;
  } else if (id < 8192) {
    in = W1; out = W1T; R = 1024; C = 4096; id -= 4096;
  } else {
    in = W2; out = W2T; R = 4096; C = 1024; id -= 8192;
  }
  const int tpc = C >> 5;
  const int c0 = (id % tpc) * 32, r0 = (id / tpc) * 32;
  __shared__ float t[32][33];
  const int tid = threadIdx.x;
  {
    const int rr = tid >> 3, c4 = (tid & 7) * 4;
    size_t addr;
    if (qkv)
      addr = (size_t)(c0 >> 6) * 65536 + (size_t)(r0 + rr) * 64 +
             ((c0 & 63) + c4);
    else
      addr = (size_t)(r0 + rr) * C + (c0 + c4);
    float4 v = *(const float4*)(in + addr);
    t[rr][c4 + 0] = v.x;
    t[rr][c4 + 1] = v.y;
    t[rr][c4 + 2] = v.z;
    t[rr][c4 + 3] = v.w;
  }
  __syncthreads();
  {
    const int cc = tid >> 3, k4 = (tid & 7) * 4;
    ushort4v hi;
    hi.x = f2bf(t[k4 + 0][cc] * scale);
    hi.y = f2bf(t[k4 + 1][cc] * scale);
    hi.z = f2bf(t[k4 + 2][cc] * scale);
    hi.w = f2bf(t[k4 + 3][cc] * scale);
    *(ushort4v*)(out + (size_t)(c0 + cc) * R + (r0 + k4)) = hi;
  }
}

// ---------------------------------------------------------------------------
// LayerNorm fp32 in -> bf16 out
// ---------------------------------------------------------------------------
__global__ __launch_bounds__(256) void ln_kernel(const float* __restrict__ x,
                                                 const float* __restrict__ g,
                                                 const float* __restrict__ b,
                                                 unsigned short* __restrict__ o) {
  const int row = blockIdx.x;
  const float* xp = x + (size_t)row * E_DIM;
  const int t4 = threadIdx.x * 4;
  float4 xv = *(const float4*)(xp + t4);
  float s = xv.x + xv.y + xv.z + xv.w;
  float ss = xv.x * xv.x + xv.y * xv.y + xv.z * xv.z + xv.w * xv.w;
#pragma unroll
  for (int off = 32; off > 0; off >>= 1) {
    s += __shfl_down(s, off);
    ss += __shfl_down(ss, off);
  }
  __shared__ float red[8];
  const int wid = threadIdx.x >> 6;
  if ((threadIdx.x & 63) == 0) {
    red[wid] = s;
    red[4 + wid] = ss;
  }
  __syncthreads();
  if (threadIdx.x == 0) {
    float S = red[0] + red[1] + red[2] + red[3];
    float SS = red[4] + red[5] + red[6] + red[7];
    float mean = S * (1.0f / E_DIM);
    float var = SS * (1.0f / E_DIM) - mean * mean;
    red[0] = mean;
    red[1] = rsqrtf(var + LN_EPS);
  }
  __syncthreads();
  const float mean = red[0], rstd = red[1];
  float4 gv = *(const float4*)(g + t4);
  float4 bv = *(const float4*)(b + t4);
  ushort4v hi;
  hi.x = f2bf((xv.x - mean) * rstd * gv.x + bv.x);
  hi.y = f2bf((xv.y - mean) * rstd * gv.y + bv.y);
  hi.z = f2bf((xv.z - mean) * rstd * gv.z + bv.z);
  hi.w = f2bf((xv.w - mean) * rstd * gv.w + bv.w);
  *(ushort4v*)(o + (size_t)row * E_DIM + t4) = hi;
}

// ---------------------------------------------------------------------------
// MFMA GEMM: C[M,N] = A[M,K] * B^T (B stored [N][K], bf16).
// m97 structure: 128x128 tile, BK=64, 4 waves, single 32KB LDS buffer,
// 2 barriers/K-step. Fragment-ordered LDS (0 bank conflicts, r4/r5).
// XCD-chunked swizzle (FETCH 135->49MB, r5). NO ATOMICS anywhere (r7: atomic
// epilogue ran at 1.09 TB/s RMW speed and dominated the kernel).
// MODE 0: fused QKV: n<1024 -> Q[pair][s][d] (log2e-scaled); <2048 -> K;
//         else Vt[pair][d][s]
// MODE 2: fp32 out = acc + bias[n] + resid[m][n]       (Wo)
// MODE 3: bf16 out = relu(acc + bias[n])               (W1)
// MODE 5: split-K over gridDim.z: plain fp32 stores to per-z partial buffer
//         out0 + z*M*N  (W2; reduced by reduce_out)
// ---------------------------------------------------------------------------
template <int MODE>
__global__ __launch_bounds__(256) void mfma_gemm(
    const unsigned short* __restrict__ A, const unsigned short* __restrict__ B,
    const float* __restrict__ bias, const float* __restrict__ bias2,
    const float* __restrict__ bias3, const float* __restrict__ resid,
    void* __restrict__ out0, void* __restrict__ out1, void* __restrict__ out2,
    int M, int N, int K) {
  __shared__ unsigned short As[8192];
  __shared__ unsigned short Bs[8192];
  const int tid = threadIdx.x;
  // XCD-chunked swizzle: contiguous swz-range per XCD -> A-panel L2 reuse.
  // nwg % 8 == 0 for all launches (256/768/1024).
  const int nwg = gridDim.x * gridDim.y;
  const int flat = blockIdx.y * gridDim.x + blockIdx.x;
  const int swz = (flat & 7) * (nwg >> 3) + (flat >> 3);
  const int m0 = (swz / gridDim.x) * 128, n0 = (swz % gridDim.x) * 128;
  const int lane = tid & 63, wid = tid >> 6;
  const int wr = wid >> 1, wc = wid & 1;
  const int lr = lane & 15, lg = lane >> 4;

  f32x4 acc[4][4];
#pragma unroll
  for (int i = 0; i < 4; ++i)
#pragma unroll
    for (int j = 0; j < 4; ++j) acc[i][j] = {0.f, 0.f, 0.f, 0.f};

  int kbeg = 0, kend = K;
  if constexpr (MODE == 5) {
    int kslice = K / gridDim.z;
    kbeg = blockIdx.z * kslice;
    kend = kbeg + kslice;
  }

  for (int k0 = kbeg; k0 < kend; k0 += 64) {
#pragma unroll
    for (int c = 0; c < 4; ++c) {
      int chunk = wid * 4 + c;  // 0..15; rb = chunk>>1, kc = chunk&1
      int rb = chunk >> 1, kc = chunk & 1;
      size_t goff = (size_t)(rb * 16 + lr) * K + k0 + kc * 32 + lg * 8;
      gload_lds16(A + (size_t)m0 * K + goff, As + chunk * 512);
      gload_lds16(B + (size_t)n0 * K + goff, Bs + chunk * 512);
    }
    __syncthreads();
#pragma unroll
    for (int kc = 0; kc < 2; ++kc) {
      short8 af[4], bf[4];
#pragma unroll
      for (int mi = 0; mi < 4; ++mi)
        af[mi] = *(const short8*)(As + ((wr * 4 + mi) * 2 + kc) * 512 + lane * 8);
#pragma unroll
      for (int ni = 0; ni < 4; ++ni)
        bf[ni] = *(const short8*)(Bs + ((wc * 4 + ni) * 2 + kc) * 512 + lane * 8);
#pragma unroll
      for (int mi = 0; mi < 4; ++mi)
#pragma unroll
        for (int ni = 0; ni < 4; ++ni)
          acc[mi][ni] = __builtin_amdgcn_mfma_f32_16x16x32_bf16(
              af[mi], bf[ni], acc[mi][ni], 0, 0, 0);
    }
    __syncthreads();
  }
  // epilogue — C/D layout: col = lane&15, row = (lane>>4)*4 + reg
  float* part;
  if constexpr (MODE == 5)
    part = (float*)out0 + (size_t)blockIdx.z * M * N;
#pragma unroll
  for (int mi = 0; mi < 4; ++mi) {
#pragma unroll
    for (int ni = 0; ni < 4; ++ni) {
      int n = n0 + wc * 64 + ni * 16 + lr;
#pragma unroll
      for (int rr = 0; rr < 4; ++rr) {
        int m = m0 + wr * 64 + mi * 16 + lg * 4 + rr;
        float v = acc[mi][ni][rr];
        if constexpr (MODE == 0) {
          int seg = n >> 10, nn = n & 1023;
          const float* bp = seg == 0 ? bias : seg == 1 ? bias2 : bias3;
          v += (seg == 0) ? bp[nn] * LOG2E : bp[nn];
          int hh = nn >> 6, d = nn & 63, bb = m >> 11, srow = m & 2047;
          size_t pb = (size_t)(hh * 2 + bb) * 131072;
          if (seg == 0)
            ((unsigned short*)out0)[pb + (size_t)srow * 64 + d] = f2bf(v);
          else if (seg == 1)
            ((unsigned short*)out1)[pb + (size_t)srow * 64 + d] = f2bf(v);
          else
            ((unsigned short*)out2)[pb + (size_t)d * 2048 + srow] = f2bf(v);
        } else if constexpr (MODE == 2) {
          size_t ad = (size_t)m * N + n;
          ((float*)out0)[ad] = v + bias[n] + resid[ad];
        } else if constexpr (MODE == 3) {
          ((unsigned short*)out0)[(size_t)m * N + n] = f2bf(fmaxf(v + bias[n], 0.f));
        } else {
          part[(size_t)m * N + n] = v;
        }
      }
    }
  }
}

// ---------------------------------------------------------------------------
// Attention (quirk-faithful): scores = K·Q^T unscaled, softmax over query t.
// Logits arrive in exp2 domain (Wq,bq pre-scaled by log2e).
// S^T = Q·K^T: lane owns ONE s-column; softmax = 2 cross-lane reduces;
// P^T B-frags for PV via lane shuffle (no LDS P). Fragment-ordered LDS tiles.
// Q,K: [pair][2048][64] bf16; Vt: [pair][64][2048]. O: [4096][1024] bf16.
// ---------------------------------------------------------------------------
__global__ __launch_bounds__(256, 4) void attn_mfma(
    const unsigned short* __restrict__ Q, const unsigned short* __restrict__ K,
    const unsigned short* __restrict__ Vt, unsigned short* __restrict__ O) {
  __shared__ unsigned short Qs[2][4096];
  __shared__ unsigned short Vs[2][4096];
  const int bid = blockIdx.x;
  const int wg = (bid & 7) * 128 + (bid >> 3);  // XCD-chunked swizzle (1024%8==0)
  const int pair = wg >> 5, stile = wg & 31;
  const int tid = threadIdx.x, lane = tid & 63, wid = tid >> 6;
  const int lr = lane & 15, lg = lane >> 4;
  const size_t pbase = (size_t)pair * 131072;

  const int s_own = stile * 64 + wid * 16 + lr;
  short8 kb[2];  // B-frag: col s = lr-owned, k = d
#pragma unroll
  for (int c = 0; c < 2; ++c)
    kb[c] = *(const short8*)(K + pbase + (size_t)s_own * 64 + c * 32 + lg * 8);

  f32x4 oa[4];
#pragma unroll
  for (int i = 0; i < 4; ++i) oa[i] = {0.f, 0.f, 0.f, 0.f};
  float mrun = -3e38f, lrun = 0.f;

  // frag-ordered staging: chunk = wid*2+c holds (rowblk=wid, kc=c), lane-linear
  auto stage = [&](int buf, int t0) {
#pragma unroll
    for (int c = 0; c < 2; ++c) {
      int chunk = wid * 2 + c;
      gload_lds16(Q + pbase + (size_t)(t0 + wid * 16 + lr) * 64 + c * 32 + lg * 8,
                  &Qs[buf][chunk * 512]);
      gload_lds16(Vt + pbase + (size_t)(wid * 16 + lr) * 2048 + t0 + c * 32 + lg * 8,
                  &Vs[buf][chunk * 512]);
    }
  };

  stage(0, 0);
  __syncthreads();

  for (int it = 0; it < 32; ++it) {
    const int cur = it & 1;
    if (it < 31) stage(cur ^ 1, (it + 1) * 64);

    // S^T tile: sacc[j][r] = S[t = j*16 + lg*4 + r][s = lr]  (log2 domain)
    f32x4 sacc[4];
#pragma unroll
    for (int j = 0; j < 4; ++j) {
      sacc[j] = {0.f, 0.f, 0.f, 0.f};
      __builtin_amdgcn_s_setprio(1);
#pragma unroll
      for (int c = 0; c < 2; ++c) {
        short8 aq = *(const short8*)(&Qs[cur][(j * 2 + c) * 512 + lane * 8]);
        sacc[j] = __builtin_amdgcn_mfma_f32_16x16x32_bf16(aq, kb[c], sacc[j], 0, 0, 0);
      }
      __builtin_amdgcn_s_setprio(0);
    }
    // online softmax (exp2 domain) with defer-max
    float tm = fmaxf(
        fmaxf(fmaxf(fmaxf(sacc[0][0], sacc[0][1]), fmaxf(sacc[0][2], sacc[0][3])),
              fmaxf(fmaxf(sacc[1][0], sacc[1][1]), fmaxf(sacc[1][2], sacc[1][3]))),
        fmaxf(fmaxf(fmaxf(sacc[2][0], sacc[2][1]), fmaxf(sacc[2][2], sacc[2][3])),
              fmaxf(fmaxf(sacc[3][0], sacc[3][1]), fmaxf(sacc[3][2], sacc[3][3]))));
    tm = fmaxf(tm, __shfl_xor(tm, 16));
    tm = fmaxf(tm, __shfl_xor(tm, 32));
    if (!__all(tm - mrun <= 11.0f)) {  // rescale path (rare after warm-up)
      float mnew = fmaxf(mrun, tm);
      float sc = exp2_fast(mrun - mnew);
      mrun = mnew;
      lrun *= sc;
#pragma unroll
      for (int di = 0; di < 4; ++di) {
        f32x4 t = oa[di];
        t[0] *= sc; t[1] *= sc; t[2] *= sc; t[3] *= sc;
        oa[di] = t;
      }
    }
    float p[4][4];
#pragma unroll
    for (int j = 0; j < 4; ++j)
#pragma unroll
      for (int r = 0; r < 4; ++r) p[j][r] = exp2_fast(sacc[j][r] - mrun);
    float lsum = ((p[0][0] + p[0][1]) + (p[0][2] + p[0][3])) +
                 ((p[1][0] + p[1][1]) + (p[1][2] + p[1][3])) +
                 ((p[2][0] + p[2][1]) + (p[2][2] + p[2][3])) +
                 ((p[3][0] + p[3][1]) + (p[3][2] + p[3][3]));
    lsum += __shfl_xor(lsum, 16);
    lsum += __shfl_xor(lsum, 32);
    lrun += lsum;
    // pack P rows (bf16 pairs) for shuffle-transpose
    unsigned int pw[4][2];
#pragma unroll
    for (int j = 0; j < 4; ++j) {
      pw[j][0] = cvt_pk_bf16(p[j][0], p[j][1]);
      pw[j][1] = cvt_pk_bf16(p[j][2], p[j][3]);
    }
    // PV: O^T[d][s] += Vt[d][t] * P^T[t][s]
#pragma unroll
    for (int kc = 0; kc < 2; ++kc) {
      unsigned int bw[4];
#pragma unroll
      for (int mm = 0; mm < 4; ++mm) {
        int src = ((lg & 1) * 2 + (mm >> 1)) * 16 + lr;
        int lo = __shfl((int)pw[2 * kc][mm & 1], src, 64);
        int hi = __shfl((int)pw[2 * kc + 1][mm & 1], src, 64);
        bw[mm] = (lg & 2) ? (unsigned)hi : (unsigned)lo;
      }
      union { unsigned int u[4]; short8 s8; } pb;
      pb.u[0] = bw[0]; pb.u[1] = bw[1]; pb.u[2] = bw[2]; pb.u[3] = bw[3];
      __builtin_amdgcn_s_setprio(1);
#pragma unroll
      for (int di = 0; di < 4; ++di) {
        short8 vf = *(const short8*)(&Vs[cur][(di * 2 + kc) * 512 + lane * 8]);
        oa[di] = __builtin_amdgcn_mfma_f32_16x16x32_bf16(vf, pb.s8, oa[di], 0, 0, 0);
      }
      __builtin_amdgcn_s_setprio(0);
    }
    __syncthreads();
  }

  const float inv = 1.f / lrun;
  const int b = pair & 1, h = pair >> 1;
  unsigned short* op = O + ((size_t)(b * 2048 + s_own)) * 1024 + h * 64;
#pragma unroll
  for (int di = 0; di < 4; ++di) {
    unsigned int w0 = cvt_pk_bf16(oa[di][0] * inv, oa[di][1] * inv);
    unsigned int w1 = cvt_pk_bf16(oa[di][2] * inv, oa[di][3] * inv);
    *(unsigned int*)(op + di * 16 + lg * 4) = w0;
    *(unsigned int*)(op + di * 16 + lg * 4 + 2) = w1;
  }
}

// ---------------------------------------------------------------------------
// reduce: out = x2 + b2[n] + sum_z P[z]  (fp32, vectorized; 4 float4/thread)
// ---------------------------------------------------------------------------
__global__ __launch_bounds__(256) void reduce_out(const float* __restrict__ P,
                                                  int nz,
                                                  const float* __restrict__ x2,
                                                  const float* __restrict__ b2,
                                                  float* __restrict__ out) {
#pragma unroll
  for (int k = 0; k < 4; ++k) {
    size_t idx = (size_t)blockIdx.x * 1024 + k * 256 + threadIdx.x;  // float4 id
    float4 v = ((const float4*)x2)[idx];
    float4 bb = ((const float4*)b2)[idx & 255];
    v.x += bb.x; v.y += bb.y; v.z += bb.z; v.w += bb.w;
    for (int z = 0; z < nz; ++z) {
      float4 p = ((const float4*)P)[(size_t)z * 1048576 + idx];
      v.x += p.x; v.y += p.y; v.z += p.z; v.w += p.w;
    }
    ((float4*)out)[idx] = v;
  }
}

// ---------------------------------------------------------------------------
extern "C" void kernel_launch(void* const* d_in, const int* in_sizes, int n_in,
                              void* d_out, int out_size, void* d_ws,
                              size_t ws_size, hipStream_t stream) {
  const float* x = (const float*)d_in[0];
  const float* Wq = (const float*)d_in[1];
  const float* bq = (const float*)d_in[2];
  const float* Wk = (const float*)d_in[3];
  const float* bk = (const float*)d_in[4];
  const float* Wv = (const float*)d_in[5];
  const float* bv = (const float*)d_in[6];
  const float* Wo = (const float*)d_in[7];
  const float* bo = (const float*)d_in[8];
  const float* ln1_g = (const float*)d_in[9];
  const float* ln1_b = (const float*)d_in[10];
  const float* ln2_g = (const float*)d_in[11];
  const float* ln2_b = (const float*)d_in[12];
  const float* W1 = (const float*)d_in[13];
  const float* b1 = (const float*)d_in[14];
  const float* W2 = (const float*)d_in[15];
  const float* b2 = (const float*)d_in[16];

  char* w = (char*)d_ws;
  const size_t MB = 1024 * 1024;
  unsigned short* WqkvT = (unsigned short*)(w + 0 * MB);  // [3072][1024]
  unsigned short* WoT = (unsigned short*)(w + 6 * MB);    // [1024][1024]
  unsigned short* W1T = (unsigned short*)(w + 8 * MB);    // [4096][1024]
  unsigned short* W2T = (unsigned short*)(w + 16 * MB);   // [1024][4096]
  unsigned short* h = (unsigned short*)(w + 24 * MB);     // [4096][1024]
  unsigned short* Qb = (unsigned short*)(w + 32 * MB);    // [32][2048][64]
  unsigned short* Kb = (unsigned short*)(w + 40 * MB);
  unsigned short* Vt = (unsigned short*)(w + 48 * MB);    // [32][64][2048]
  unsigned short* Obuf = (unsigned short*)(w + 56 * MB);  // [4096][1024]
  unsigned short* m1 = (unsigned short*)(w + 32 * MB);    // [4096][4096], aliases Qb..Obuf
  float* x2 = (float*)(w + 64 * MB);                      // [4096][1024] fp32
  float* Pz = (float*)(w + 80 * MB);                      // nz x 16 MB partials

  // split-K factor for W2 gated by available workspace (no atomics).
  int nz = (ws_size >= 145 * MB) ? 4 : (ws_size >= 113 * MB) ? 2 : 1;

  const dim3 blk(256);

  transpose_all<<<12288, blk, 0, stream>>>(Wq, Wk, Wv, Wo, W1, W2, WqkvT, WoT,
                                           W1T, W2T);

  ln_kernel<<<M_DIM, blk, 0, stream>>>(x, ln1_g, ln1_b, h);

  mfma_gemm<0><<<dim3(24, 32), blk, 0, stream>>>(h, WqkvT, bq, bk, bv, nullptr,
                                                 Qb, Kb, Vt, M_DIM, 3072, 1024);

  attn_mfma<<<1024, blk, 0, stream>>>(Qb, Kb, Vt, Obuf);

  mfma_gemm<2><<<dim3(8, 32), blk, 0, stream>>>(Obuf, WoT, bo, nullptr, nullptr,
                                                x, x2, nullptr, nullptr, M_DIM,
                                                1024, 1024);

  ln_kernel<<<M_DIM, blk, 0, stream>>>(x2, ln2_g, ln2_b, h);

  mfma_gemm<3><<<dim3(32, 32), blk, 0, stream>>>(h, W1T, b1, nullptr, nullptr,
                                                 nullptr, m1, nullptr, nullptr,
                                                 M_DIM, 4096, 1024);

  mfma_gemm<5><<<dim3(8, 32, nz), blk, 0, stream>>>(
      m1, W2T, nullptr, nullptr, nullptr, nullptr, Pz, nullptr, nullptr, M_DIM,
      1024, 4096);

  reduce_out<<<1024, blk, 0, stream>>>(Pz, nz, x2, b2, (float*)d_out);
}

// Round 9
// 466.257 us; speedup vs baseline: 1.1048x; 1.0178x over previous
//
#include <hip/hip_runtime.h>
#include <cstdint>
#include <cstddef>

typedef __attribute__((ext_vector_type(8))) short short8;
typedef __attribute__((ext_vector_type(4))) float f32x4;
typedef __attribute__((ext_vector_type(4))) unsigned short ushort4v;

#define E_DIM 1024
#define D_DIM 64
#define H_DIM 16
#define F_DIM 4096
#define B_DIM 2
#define S_DIM 2048
#define M_DIM 4096
#define LN_EPS 1e-5f
#define LOG2E 1.4426950408889634f

__device__ __forceinline__ float bf2f(unsigned short u) {
  union { unsigned int i; float f; } v;
  v.i = ((unsigned int)u) << 16;
  return v.f;
}
__device__ __forceinline__ unsigned short f2bf(float f) {
  union { float f; unsigned int i; } v;
  v.f = f;
  unsigned int r = v.i + 0x7FFFu + ((v.i >> 16) & 1u);
  return (unsigned short)(r >> 16);
}
// packed f32x2 -> bf16x2 (low word = a, high word = b), RNE
__device__ __forceinline__ unsigned int cvt_pk_bf16(float a, float b) {
  unsigned int r;
  asm("v_cvt_pk_bf16_f32 %0, %1, %2" : "=v"(r) : "v"(a), "v"(b));
  return r;
}
__device__ __forceinline__ float exp2_fast(float x) {
  float r;
  asm("v_exp_f32 %0, %1" : "=v"(r) : "v"(x));
  return r;
}

__device__ __forceinline__ void gload_lds16(const unsigned short* src,
                                            unsigned short* dst) {
  __builtin_amdgcn_global_load_lds(
      (const __attribute__((address_space(1))) void*)src,
      (__attribute__((address_space(3))) void*)dst, 16, 0, 0);
}

// ---------------------------------------------------------------------------
// All weight transposes in ONE launch. fp32 [R][C] -> bf16 [C][R].
// block id ranges: [0,3072) Wq/Wk/Wv (QKV [H][E][D] addressing),
// [3072,4096) Wo, [4096,8192) W1, [8192,12288) W2.
// ---------------------------------------------------------------------------
__global__ __launch_bounds__(256) void transpose_all(
    const float* __restrict__ Wq, const float* __restrict__ Wk,
    const float* __restrict__ Wv, const float* __restrict__ Wo,
    const float* __restrict__ W1, const float* __restrict__ W2,
    unsigned short* __restrict__ WqkvT, unsigned short* __restrict__ WoT,
    unsigned short* __restrict__ W1T, unsigned short* __restrict__ W2T) {
  int id = blockIdx.x;
  const float* in;
  unsigned short* out;
  int R, C;
  bool qkv = false;
  float scale = 1.f;
  if (id < 3072) {
    int seg = id >> 10;
    in = seg == 0 ? Wq : seg == 1 ? Wk : Wv;
    out = WqkvT + (size_t)seg * 1048576;
    R = 1024; C = 1024; qkv = true;
    if (seg == 0) scale = LOG2E;
    id &= 1023;
  } else if (id < 4096) {
    in = Wo; out = WoT; R = 1024; C = 1024; id -= 3072;
  } else if (id < 8192) {
    in = W1; out = W1T; R = 1024; C = 4096; id -= 4096;
  } else {
    in = W2; out = W2T; R = 4096; C = 1024; id -= 8192;
  }
  const int tpc = C >> 5;
  const int c0 = (id % tpc) * 32, r0 = (id / tpc) * 32;
  __shared__ float t[32][33];
  const int tid = threadIdx.x;
  {
    const int rr = tid >> 3, c4 = (tid & 7) * 4;
    size_t addr;
    if (qkv)
      addr = (size_t)(c0 >> 6) * 65536 + (size_t)(r0 + rr) * 64 +
             ((c0 & 63) + c4);
    else
      addr = (size_t)(r0 + rr) * C + (c0 + c4);
    float4 v = *(const float4*)(in + addr);
    t[rr][c4 + 0] = v.x;
    t[rr][c4 + 1] = v.y;
    t[rr][c4 + 2] = v.z;
    t[rr][c4 + 3] = v.w;
  }
  __syncthreads();
  {
    const int cc = tid >> 3, k4 = (tid & 7) * 4;
    ushort4v hi;
    hi.x = f2bf(t[k4 + 0][cc] * scale);
    hi.y = f2bf(t[k4 + 1][cc] * scale);
    hi.z = f2bf(t[k4 + 2][cc] * scale);
    hi.w = f2bf(t[k4 + 3][cc] * scale);
    *(ushort4v*)(out + (size_t)(c0 + cc) * R + (r0 + k4)) = hi;
  }
}

// ---------------------------------------------------------------------------
// LayerNorm fp32 in -> bf16 out
// ---------------------------------------------------------------------------
__global__ __launch_bounds__(256) void ln_kernel(const float* __restrict__ x,
                                                 const float* __restrict__ g,
                                                 const float* __restrict__ b,
                                                 unsigned short* __restrict__ o) {
  const int row = blockIdx.x;
  const float* xp = x + (size_t)row * E_DIM;
  const int t4 = threadIdx.x * 4;
  float4 xv = *(const float4*)(xp + t4);
  float s = xv.x + xv.y + xv.z + xv.w;
  float ss = xv.x * xv.x + xv.y * xv.y + xv.z * xv.z + xv.w * xv.w;
#pragma unroll
  for (int off = 32; off > 0; off >>= 1) {
    s += __shfl_down(s, off);
    ss += __shfl_down(ss, off);
  }
  __shared__ float red[8];
  const int wid = threadIdx.x >> 6;
  if ((threadIdx.x & 63) == 0) {
    red[wid] = s;
    red[4 + wid] = ss;
  }
  __syncthreads();
  if (threadIdx.x == 0) {
    float S = red[0] + red[1] + red[2] + red[3];
    float SS = red[4] + red[5] + red[6] + red[7];
    float mean = S * (1.0f / E_DIM);
    float var = SS * (1.0f / E_DIM) - mean * mean;
    red[0] = mean;
    red[1] = rsqrtf(var + LN_EPS);
  }
  __syncthreads();
  const float mean = red[0], rstd = red[1];
  float4 gv = *(const float4*)(g + t4);
  float4 bv = *(const float4*)(b + t4);
  ushort4v hi;
  hi.x = f2bf((xv.x - mean) * rstd * gv.x + bv.x);
  hi.y = f2bf((xv.y - mean) * rstd * gv.y + bv.y);
  hi.z = f2bf((xv.z - mean) * rstd * gv.z + bv.z);
  hi.w = f2bf((xv.w - mean) * rstd * gv.w + bv.w);
  *(ushort4v*)(o + (size_t)row * E_DIM + t4) = hi;
}

// ---------------------------------------------------------------------------
// MFMA GEMM: C[M,N] = A[M,K] * B^T (B stored [N][K], bf16).
// 128x128 tile, BK=64, 4 waves, T3 2-phase double-buffer (m228d: 622 TF
// refcheck'd at this exact config): stage(next) BEFORE compute(cur), ONE
// barrier per K-step (drain after MFMA => stage latency hides under MFMA),
// setprio(1) around MFMA cluster. Fragment-ordered LDS (0 bank conflicts,
// r4/r5). XCD-chunked swizzle (FETCH 135->49MB, r5). No atomics (r7/r8).
// MODE 0: fused QKV: n<1024 -> Q[pair][s][d] (log2e-scaled); <2048 -> K;
//         else Vt[pair][d][s]
// MODE 2: fp32 out = acc + bias[n] + resid[m][n]       (Wo)
// MODE 3: bf16 out = relu(acc + bias[n])               (W1)
// MODE 5: split-K over gridDim.z: plain fp32 stores to per-z partial buffer
//         out0 + z*M*N  (W2; reduced by reduce_out)
// ---------------------------------------------------------------------------
template <int MODE>
__global__ __launch_bounds__(256) void mfma_gemm(
    const unsigned short* __restrict__ A, const unsigned short* __restrict__ B,
    const float* __restrict__ bias, const float* __restrict__ bias2,
    const float* __restrict__ bias3, const float* __restrict__ resid,
    void* __restrict__ out0, void* __restrict__ out1, void* __restrict__ out2,
    int M, int N, int K) {
  __shared__ unsigned short As[2][8192];
  __shared__ unsigned short Bs[2][8192];
  const int tid = threadIdx.x;
  // XCD-chunked swizzle: contiguous swz-range per XCD -> A-panel L2 reuse.
  // nwg % 8 == 0 for all launches (256/768/1024).
  const int nwg = gridDim.x * gridDim.y;
  const int flat = blockIdx.y * gridDim.x + blockIdx.x;
  const int swz = (flat & 7) * (nwg >> 3) + (flat >> 3);
  const int m0 = (swz / gridDim.x) * 128, n0 = (swz % gridDim.x) * 128;
  const int lane = tid & 63, wid = tid >> 6;
  const int wr = wid >> 1, wc = wid & 1;
  const int lr = lane & 15, lg = lane >> 4;

  f32x4 acc[4][4];
#pragma unroll
  for (int i = 0; i < 4; ++i)
#pragma unroll
    for (int j = 0; j < 4; ++j) acc[i][j] = {0.f, 0.f, 0.f, 0.f};

  int kbeg = 0, kend = K;
  if constexpr (MODE == 5) {
    int kslice = K / gridDim.z;
    kbeg = blockIdx.z * kslice;
    kend = kbeg + kslice;
  }

  auto stage = [&](int buf, int k0) {
#pragma unroll
    for (int c = 0; c < 4; ++c) {
      int chunk = wid * 4 + c;  // 0..15; rb = chunk>>1, kc = chunk&1
      int rb = chunk >> 1, kc = chunk & 1;
      size_t goff = (size_t)(rb * 16 + lr) * K + k0 + kc * 32 + lg * 8;
      gload_lds16(A + (size_t)m0 * K + goff, &As[buf][chunk * 512]);
      gload_lds16(B + (size_t)n0 * K + goff, &Bs[buf][chunk * 512]);
    }
  };

  const int nt = (kend - kbeg) / 64;
  stage(0, kbeg);
  __syncthreads();
  int cur = 0;

  for (int t = 0; t < nt; ++t) {
    if (t + 1 < nt) stage(cur ^ 1, kbeg + (t + 1) * 64);
#pragma unroll
    for (int kc = 0; kc < 2; ++kc) {
      short8 af[4], bf[4];
#pragma unroll
      for (int mi = 0; mi < 4; ++mi)
        af[mi] = *(const short8*)(&As[cur][((wr * 4 + mi) * 2 + kc) * 512 + lane * 8]);
#pragma unroll
      for (int ni = 0; ni < 4; ++ni)
        bf[ni] = *(const short8*)(&Bs[cur][((wc * 4 + ni) * 2 + kc) * 512 + lane * 8]);
      __builtin_amdgcn_s_setprio(1);
#pragma unroll
      for (int mi = 0; mi < 4; ++mi)
#pragma unroll
        for (int ni = 0; ni < 4; ++ni)
          acc[mi][ni] = __builtin_amdgcn_mfma_f32_16x16x32_bf16(
              af[mi], bf[ni], acc[mi][ni], 0, 0, 0);
      __builtin_amdgcn_s_setprio(0);
    }
    __syncthreads();  // one drain/step: waits stage(next) + guards cur reuse
    cur ^= 1;
  }
  // epilogue — C/D layout: col = lane&15, row = (lane>>4)*4 + reg
  float* part;
  if constexpr (MODE == 5)
    part = (float*)out0 + (size_t)blockIdx.z * M * N;
#pragma unroll
  for (int mi = 0; mi < 4; ++mi) {
#pragma unroll
    for (int ni = 0; ni < 4; ++ni) {
      int n = n0 + wc * 64 + ni * 16 + lr;
#pragma unroll
      for (int rr = 0; rr < 4; ++rr) {
        int m = m0 + wr * 64 + mi * 16 + lg * 4 + rr;
        float v = acc[mi][ni][rr];
        if constexpr (MODE == 0) {
          int seg = n >> 10, nn = n & 1023;
          const float* bp = seg == 0 ? bias : seg == 1 ? bias2 : bias3;
          v += (seg == 0) ? bp[nn] * LOG2E : bp[nn];
          int hh = nn >> 6, d = nn & 63, bb = m >> 11, srow = m & 2047;
          size_t pb = (size_t)(hh * 2 + bb) * 131072;
          if (seg == 0)
            ((unsigned short*)out0)[pb + (size_t)srow * 64 + d] = f2bf(v);
          else if (seg == 1)
            ((unsigned short*)out1)[pb + (size_t)srow * 64 + d] = f2bf(v);
          else
            ((unsigned short*)out2)[pb + (size_t)d * 2048 + srow] = f2bf(v);
        } else if constexpr (MODE == 2) {
          size_t ad = (size_t)m * N + n;
          ((float*)out0)[ad] = v + bias[n] + resid[ad];
        } else if constexpr (MODE == 3) {
          ((unsigned short*)out0)[(size_t)m * N + n] = f2bf(fmaxf(v + bias[n], 0.f));
        } else {
          part[(size_t)m * N + n] = v;
        }
      }
    }
  }
}

// ---------------------------------------------------------------------------
// Attention (quirk-faithful): scores = K·Q^T unscaled, softmax over query t.
// Logits arrive in exp2 domain (Wq,bq pre-scaled by log2e).
// S^T = Q·K^T: lane owns ONE s-column; softmax = 2 cross-lane reduces;
// P^T B-frags for PV via lane shuffle (no LDS P). Fragment-ordered LDS tiles.
// Q,K: [pair][2048][64] bf16; Vt: [pair][64][2048]. O: [4096][1024] bf16.
// ---------------------------------------------------------------------------
__global__ __launch_bounds__(256, 4) void attn_mfma(
    const unsigned short* __restrict__ Q, const unsigned short* __restrict__ K,
    const unsigned short* __restrict__ Vt, unsigned short* __restrict__ O) {
  __shared__ unsigned short Qs[2][4096];
  __shared__ unsigned short Vs[2][4096];
  const int bid = blockIdx.x;
  const int wg = (bid & 7) * 128 + (bid >> 3);  // XCD-chunked swizzle (1024%8==0)
  const int pair = wg >> 5, stile = wg & 31;
  const int tid = threadIdx.x, lane = tid & 63, wid = tid >> 6;
  const int lr = lane & 15, lg = lane >> 4;
  const size_t pbase = (size_t)pair * 131072;

  const int s_own = stile * 64 + wid * 16 + lr;
  short8 kb[2];  // B-frag: col s = lr-owned, k = d
#pragma unroll
  for (int c = 0; c < 2; ++c)
    kb[c] = *(const short8*)(K + pbase + (size_t)s_own * 64 + c * 32 + lg * 8);

  f32x4 oa[4];
#pragma unroll
  for (int i = 0; i < 4; ++i) oa[i] = {0.f, 0.f, 0.f, 0.f};
  float mrun = -3e38f, lrun = 0.f;

  // frag-ordered staging: chunk = wid*2+c holds (rowblk=wid, kc=c), lane-linear
  auto stage = [&](int buf, int t0) {
#pragma unroll
    for (int c = 0; c < 2; ++c) {
      int chunk = wid * 2 + c;
      gload_lds16(Q + pbase + (size_t)(t0 + wid * 16 + lr) * 64 + c * 32 + lg * 8,
                  &Qs[buf][chunk * 512]);
      gload_lds16(Vt + pbase + (size_t)(wid * 16 + lr) * 2048 + t0 + c * 32 + lg * 8,
                  &Vs[buf][chunk * 512]);
    }
  };

  stage(0, 0);
  __syncthreads();

  for (int it = 0; it < 32; ++it) {
    const int cur = it & 1;
    if (it < 31) stage(cur ^ 1, (it + 1) * 64);

    // S^T tile: sacc[j][r] = S[t = j*16 + lg*4 + r][s = lr]  (log2 domain)
    f32x4 sacc[4];
#pragma unroll
    for (int j = 0; j < 4; ++j) {
      sacc[j] = {0.f, 0.f, 0.f, 0.f};
      __builtin_amdgcn_s_setprio(1);
#pragma unroll
      for (int c = 0; c < 2; ++c) {
        short8 aq = *(const short8*)(&Qs[cur][(j * 2 + c) * 512 + lane * 8]);
        sacc[j] = __builtin_amdgcn_mfma_f32_16x16x32_bf16(aq, kb[c], sacc[j], 0, 0, 0);
      }
      __builtin_amdgcn_s_setprio(0);
    }
    // online softmax (exp2 domain) with defer-max
    float tm = fmaxf(
        fmaxf(fmaxf(fmaxf(sacc[0][0], sacc[0][1]), fmaxf(sacc[0][2], sacc[0][3])),
              fmaxf(fmaxf(sacc[1][0], sacc[1][1]), fmaxf(sacc[1][2], sacc[1][3]))),
        fmaxf(fmaxf(fmaxf(sacc[2][0], sacc[2][1]), fmaxf(sacc[2][2], sacc[2][3])),
              fmaxf(fmaxf(sacc[3][0], sacc[3][1]), fmaxf(sacc[3][2], sacc[3][3]))));
    tm = fmaxf(tm, __shfl_xor(tm, 16));
    tm = fmaxf(tm, __shfl_xor(tm, 32));
    if (!__all(tm - mrun <= 11.0f)) {  // rescale path (rare after warm-up)
      float mnew = fmaxf(mrun, tm);
      float sc = exp2_fast(mrun - mnew);
      mrun = mnew;
      lrun *= sc;
#pragma unroll
      for (int di = 0; di < 4; ++di) {
        f32x4 t = oa[di];
        t[0] *= sc; t[1] *= sc; t[2] *= sc; t[3] *= sc;
        oa[di] = t;
      }
    }
    float p[4][4];
#pragma unroll
    for (int j = 0; j < 4; ++j)
#pragma unroll
      for (int r = 0; r < 4; ++r) p[j][r] = exp2_fast(sacc[j][r] - mrun);
    float lsum = ((p[0][0] + p[0][1]) + (p[0][2] + p[0][3])) +
                 ((p[1][0] + p[1][1]) + (p[1][2] + p[1][3])) +
                 ((p[2][0] + p[2][1]) + (p[2][2] + p[2][3])) +
                 ((p[3][0] + p[3][1]) + (p[3][2] + p[3][3]));
    lsum += __shfl_xor(lsum, 16);
    lsum += __shfl_xor(lsum, 32);
    lrun += lsum;
    // pack P rows (bf16 pairs) for shuffle-transpose
    unsigned int pw[4][2];
#pragma unroll
    for (int j = 0; j < 4; ++j) {
      pw[j][0] = cvt_pk_bf16(p[j][0], p[j][1]);
      pw[j][1] = cvt_pk_bf16(p[j][2], p[j][3]);
    }
    // PV: O^T[d][s] += Vt[d][t] * P^T[t][s]
#pragma unroll
    for (int kc = 0; kc < 2; ++kc) {
      unsigned int bw[4];
#pragma unroll
      for (int mm = 0; mm < 4; ++mm) {
        int src = ((lg & 1) * 2 + (mm >> 1)) * 16 + lr;
        int lo = __shfl((int)pw[2 * kc][mm & 1], src, 64);
        int hi = __shfl((int)pw[2 * kc + 1][mm & 1], src, 64);
        bw[mm] = (lg & 2) ? (unsigned)hi : (unsigned)lo;
      }
      union { unsigned int u[4]; short8 s8; } pb;
      pb.u[0] = bw[0]; pb.u[1] = bw[1]; pb.u[2] = bw[2]; pb.u[3] = bw[3];
      __builtin_amdgcn_s_setprio(1);
#pragma unroll
      for (int di = 0; di < 4; ++di) {
        short8 vf = *(const short8*)(&Vs[cur][(di * 2 + kc) * 512 + lane * 8]);
        oa[di] = __builtin_amdgcn_mfma_f32_16x16x32_bf16(vf, pb.s8, oa[di], 0, 0, 0);
      }
      __builtin_amdgcn_s_setprio(0);
    }
    __syncthreads();
  }

  const float inv = 1.f / lrun;
  const int b = pair & 1, h = pair >> 1;
  unsigned short* op = O + ((size_t)(b * 2048 + s_own)) * 1024 + h * 64;
#pragma unroll
  for (int di = 0; di < 4; ++di) {
    unsigned int w0 = cvt_pk_bf16(oa[di][0] * inv, oa[di][1] * inv);
    unsigned int w1 = cvt_pk_bf16(oa[di][2] * inv, oa[di][3] * inv);
    *(unsigned int*)(op + di * 16 + lg * 4) = w0;
    *(unsigned int*)(op + di * 16 + lg * 4 + 2) = w1;
  }
}

// ---------------------------------------------------------------------------
// reduce: out = x2 + b2[n] + sum_z P[z]  (fp32, vectorized; 4 float4/thread)
// ---------------------------------------------------------------------------
__global__ __launch_bounds__(256) void reduce_out(const float* __restrict__ P,
                                                  int nz,
                                                  const float* __restrict__ x2,
                                                  const float* __restrict__ b2,
                                                  float* __restrict__ out) {
#pragma unroll
  for (int k = 0; k < 4; ++k) {
    size_t idx = (size_t)blockIdx.x * 1024 + k * 256 + threadIdx.x;  // float4 id
    float4 v = ((const float4*)x2)[idx];
    float4 bb = ((const float4*)b2)[idx & 255];
    v.x += bb.x; v.y += bb.y; v.z += bb.z; v.w += bb.w;
    for (int z = 0; z < nz; ++z) {
      float4 p = ((const float4*)P)[(size_t)z * 1048576 + idx];
      v.x += p.x; v.y += p.y; v.z += p.z; v.w += p.w;
    }
    ((float4*)out)[idx] = v;
  }
}

// ---------------------------------------------------------------------------
extern "C" void kernel_launch(void* const* d_in, const int* in_sizes, int n_in,
                              void* d_out, int out_size, void* d_ws,
                              size_t ws_size, hipStream_t stream) {
  const float* x = (const float*)d_in[0];
  const float* Wq = (const float*)d_in[1];
  const float* bq = (const float*)d_in[2];
  const float* Wk = (const float*)d_in[3];
  const float* bk = (const float*)d_in[4];
  const float* Wv = (const float*)d_in[5];
  const float* bv = (const float*)d_in[6];
  const float* Wo = (const float*)d_in[7];
  const float* bo = (const float*)d_in[8];
  const float* ln1_g = (const float*)d_in[9];
  const float* ln1_b = (const float*)d_in[10];
  const float* ln2_g = (const float*)d_in[11];
  const float* ln2_b = (const float*)d_in[12];
  const float* W1 = (const float*)d_in[13];
  const float* b1 = (const float*)d_in[14];
  const float* W2 = (const float*)d_in[15];
  const float* b2 = (const float*)d_in[16];

  char* w = (char*)d_ws;
  const size_t MB = 1024 * 1024;
  unsigned short* WqkvT = (unsigned short*)(w + 0 * MB);  // [3072][1024]
  unsigned short* WoT = (unsigned short*)(w + 6 * MB);    // [1024][1024]
  unsigned short* W1T = (unsigned short*)(w + 8 * MB);    // [4096][1024]
  unsigned short* W2T = (unsigned short*)(w + 16 * MB);   // [1024][4096]
  unsigned short* h = (unsigned short*)(w + 24 * MB);     // [4096][1024]
  unsigned short* Qb = (unsigned short*)(w + 32 * MB);    // [32][2048][64]
  unsigned short* Kb = (unsigned short*)(w + 40 * MB);
  unsigned short* Vt = (unsigned short*)(w + 48 * MB);    // [32][64][2048]
  unsigned short* Obuf = (unsigned short*)(w + 56 * MB);  // [4096][1024]
  unsigned short* m1 = (unsigned short*)(w + 32 * MB);    // [4096][4096], aliases Qb..Obuf
  float* x2 = (float*)(w + 64 * MB);                      // [4096][1024] fp32
  float* Pz = (float*)(w + 80 * MB);                      // nz x 16 MB partials

  // split-K factor for W2 gated by available workspace (no atomics).
  int nz = (ws_size >= 145 * MB) ? 4 : (ws_size >= 113 * MB) ? 2 : 1;

  const dim3 blk(256);

  transpose_all<<<12288, blk, 0, stream>>>(Wq, Wk, Wv, Wo, W1, W2, WqkvT, WoT,
                                           W1T, W2T);

  ln_kernel<<<M_DIM, blk, 0, stream>>>(x, ln1_g, ln1_b, h);

  mfma_gemm<0><<<dim3(24, 32), blk, 0, stream>>>(h, WqkvT, bq, bk, bv, nullptr,
                                                 Qb, Kb, Vt, M_DIM, 3072, 1024);

  attn_mfma<<<1024, blk, 0, stream>>>(Qb, Kb, Vt, Obuf);

  mfma_gemm<2><<<dim3(8, 32), blk, 0, stream>>>(Obuf, WoT, bo, nullptr, nullptr,
                                                x, x2, nullptr, nullptr, M_DIM,
                                                1024, 1024);

  ln_kernel<<<M_DIM, blk, 0, stream>>>(x2, ln2_g, ln2_b, h);

  mfma_gemm<3><<<dim3(32, 32), blk, 0, stream>>>(h, W1T, b1, nullptr, nullptr,
                                                 nullptr, m1, nullptr, nullptr,
                                                 M_DIM, 4096, 1024);

  mfma_gemm<5><<<dim3(8, 32, nz), blk, 0, stream>>>(
      m1, W2T, nullptr, nullptr, nullptr, nullptr, Pz, nullptr, nullptr, M_DIM,
      1024, 4096);

  reduce_out<<<1024, blk, 0, stream>>>(Pz, nz, x2, b2, (float*)d_out);
}